// Round 11
// baseline (215.176 us; speedup 1.0000x reference)
//
#include <hip/hip_runtime.h>
#include <math.h>

// ============================================================================
// Sizes (fixed): N=2, C=64, Hax=56, W=56 -> B=112, H=56, OUT=64, N_HASHES=4,
// CHUNK=25, GROUPS=8, GP=8, hash_buckets=2, padding=19, K=3, qkv ch=96.
// RESOLVED (R8-R10 instrumentation): inputs fp32, OUTPUT FP32 (not bf16!),
// reference uses STABLE argsort tie order (jax semantics). R10's on-device
// 6-variant comparison matched ONLY the stable pipeline at ref[0]=-0.046875.
//
// ws layout (float slots):
//   qkv : [112][5376]   off 0
//   bsb : [112][2400]   off 602112
//   Rb  : [112][38400]  off 870912
//   fin : [112][3584]   off 5171712
//   idx : [112][224]    off 5573120  (int)
// ============================================================================

#define EPSN 5e-5f

__device__ __forceinline__ float dot4(const float4 a, const float4 b) {
    return a.x * b.x + a.y * b.y + a.z * b.z + a.w * b.w;
}
__device__ __forceinline__ void fma4(float4& a, float s, const float4 v) {
    a.x += s * v.x; a.y += s * v.y; a.z += s * v.z; a.w += s * v.w;
}

// ---------------- K1: qkv = conv_w @ x  (+BN affine) ----------------
__global__ __launch_bounds__(256) void k1_qkv(
        const float* __restrict__ x, const float* __restrict__ cw,
        const float* __restrict__ gamma, const float* __restrict__ beta,
        float* __restrict__ qkv) {
    __shared__ float xs[64 * 56];    // [c][h] for this b
    __shared__ float cws[96 * 64];
    const int b = blockIdx.x;
    const int n = b / 56, w = b % 56;
    const int tid = threadIdx.x;
    const float* xb = x + n * 200704 + w;
    for (int idx = tid; idx < 64 * 56; idx += 256) {
        int c = idx / 56, h = idx % 56;
        xs[idx] = xb[c * 3136 + h * 56];
    }
    for (int idx = tid; idx < 96 * 64; idx += 256) cws[idx] = cw[idx];
    __syncthreads();
    const float inv_s = 1.0f / sqrtf(1.0f + 1.0e-5f);
    for (int idx = tid; idx < 96 * 56; idx += 256) {
        int o = idx / 56, h = idx % 56;
        float s = 0.f;
        #pragma unroll 8
        for (int c = 0; c < 64; ++c) s += cws[o * 64 + c] * xs[c * 56 + h];
        qkv[b * 5376 + idx] = s * inv_s * gamma[o] + beta[o];
    }
}

// ---------------- K2: LSH codes + STABLE argsort (jax semantics) ----------------
__global__ __launch_bounds__(256) void k2_sort(
        const float* __restrict__ qkv, const float* __restrict__ rot,
        int* __restrict__ idx_buf) {
    __shared__ float wm[56 * 32];  // w_match[t][f]
    __shared__ float rl[128];      // rotations[f][u]
    __shared__ int code[224];
    __shared__ int srt[224];
    const int b = blockIdx.x, tid = threadIdx.x;
    for (int i = tid; i < 1792; i += 256) {
        wm[i] = qkv[b * 5376 + (i >> 5) * 96 + (i & 31)];
    }
    if (tid < 128) rl[tid] = rot[tid];
    __syncthreads();
    if (tid < 224) {
        int u = tid / 56, t = tid % 56;
        float s = 0.f;
        #pragma unroll 8
        for (int f = 0; f < 32; ++f) s += wm[t * 32 + f] * rl[f * 4 + u];
        code[tid] = ((s < 0.f) ? 1 : 0) + 2 * u;   // argmax([s,-s]) + u*hash_buckets
    }
    __syncthreads();
    if (tid < 224) {
        int c = code[tid], r = 0;
        for (int p = 0; p < 224; ++p) {
            int cp = code[p];
            r += (int)((cp < c) | ((cp == c) & (p < tid)));  // stable rank
        }
        srt[r] = tid;
    }
    __syncthreads();
    if (tid < 224) idx_buf[b * 224 + tid] = srt[tid];
}

// ---------------- K3: chunked attention, one block per (b,u,k) ----------------
__global__ __launch_bounds__(256) void k3_attn(
        const float* __restrict__ qkv, const int* __restrict__ idx_buf,
        const float* __restrict__ rel, float* __restrict__ Rb,
        float* __restrict__ bsb) {
    __shared__ __align__(16) float Wb[8][3][25][4];
    __shared__ float NI[8][3][25];
    __shared__ __align__(16) float Vb[8][3][25][8];
    __shared__ __align__(16) float WE[3][25][4];
    __shared__ __align__(16) float VE[3][25][8];
    __shared__ float DI[25][76];
    const int b = blockIdx.x, u = blockIdx.y, k = blockIdx.z;
    const int tid = threadIdx.x;
    const int km1 = (k + 2) % 3, kp1 = (k + 1) % 3;
    const float* q = qkv + b * 5376;
    const int* ib = idx_buf + b * 224;

    for (int idx = tid; idx < 2400; idx += 256) {
        int e = idx & 3, i = (idx >> 2) % 25, kk = (idx / 100) % 3, g = idx / 300;
        int p = 1200 * g + 300 * u + 100 * kk + 4 * i + e;
        int h = p / 2400, r = p % 2400, t = r >> 5, f = r & 31;
        int row = (t < 56) ? t : t - 19;
        int tt = ib[h * 56 + row] % 56;
        Wb[g][kk][i][e] = q[tt * 96 + f];
    }
    for (int idx = tid; idx < 4800; idx += 256) {
        int e = idx & 7, i = (idx >> 3) % 25, kk = (idx / 200) % 3, g = idx / 600;
        int p = 2400 * g + 600 * u + 200 * kk + 8 * i + e;
        int h = p / 4800, r = p % 4800, t = r >> 6, f = r & 63;
        int row = (t < 56) ? t : t - 19;
        int tt = ib[h * 56 + row] % 56;
        Vb[g][kk][i][e] = q[tt * 96 + 32 + f];
    }
    for (int idx = tid; idx < 300; idx += 256) {
        int e = idx & 3, i = (idx >> 2) % 25, kk = idx / 100;
        int t = kk * 25 + i; int row = (t < 56) ? t : t - 19;
        WE[kk][i][e] = rel[row * 12 + e];
    }
    for (int idx = tid; idx < 600; idx += 256) {
        int e = idx & 7, i = (idx >> 3) % 25, kk = idx / 200;
        int t = kk * 25 + i; int row = (t < 56) ? t : t - 19;
        VE[kk][i][e] = rel[row * 12 + 4 + e];
    }
    __syncthreads();
    for (int idx = tid; idx < 600; idx += 256) {
        int i = idx % 25, kk = (idx / 25) % 3, g = idx / 75;
        float4 v = *(const float4*)&Wb[g][kk][i][0];
        NI[g][kk][i] = 1.0f / fmaxf(sqrtf(dot4(v, v)), EPSN);
    }
    __syncthreads();
    for (int idx = tid; idx < 1875; idx += 256) {
        int i = idx / 75, j = idx % 75;
        int jb = j / 25, jj = j % 25;
        int ks = (jb == 0) ? k : ((jb == 1) ? km1 : kp1);
        float4 we = *(const float4*)&WE[ks][jj][0];
        float s2 = 0.f;
        #pragma unroll
        for (int g = 0; g < 8; ++g) {
            float4 wb = *(const float4*)&Wb[g][k][i][0];
            float4 wo = *(const float4*)&Wb[g][ks][jj][0];
            float raw = dot4(wb, wo) * NI[g][ks][jj];
            float emb = 0.1f * dot4(wb, we);
            s2 += raw * raw + emb * emb;
        }
        DI[i][j] = 1.0f / fmaxf(sqrtf(s2), EPSN);
    }
    __syncthreads();
    if (tid < 200) {
        const int g = tid & 7, i = tid >> 3;
        const float4 wb = *(const float4*)&Wb[g][k][i][0];
        float ssv[75];
        float m = -INFINITY;
        #pragma unroll
        for (int j = 0; j < 75; ++j) {
            const int jb = j / 25, jj = j % 25;
            const int ks = (jb == 0) ? k : ((jb == 1) ? km1 : kp1);
            float4 wo = *(const float4*)&Wb[g][ks][jj][0];
            float raw = dot4(wb, wo) * NI[g][ks][jj];
            float4 we = *(const float4*)&WE[ks][jj][0];
            float emb = 0.1f * dot4(wb, we);
            float v = (raw + emb) * DI[i][j];
            ssv[j] = v;
            m = fmaxf(m, v);
        }
        float se = 0.f;
        #pragma unroll
        for (int j = 0; j < 75; ++j) { float e = expf(ssv[j] - m); ssv[j] = e; se += e; }
        bsb[b * 2400 + g * 300 + u * 75 + k * 25 + i] = m + logf(se);
        const float rinv = 1.0f / se;
        float4 a0 = {0,0,0,0}, a1 = {0,0,0,0}, a2 = {0,0,0,0}, a3 = {0,0,0,0};
        #pragma unroll
        for (int j = 0; j < 75; ++j) {
            float sc = ssv[j] * rinv;
            const int jb = j / 25, jj = j % 25;
            const int ks = (jb == 0) ? k : ((jb == 1) ? km1 : kp1);
            const float4* vv = (const float4*)&Vb[g][ks][jj][0];
            fma4(a0, sc, vv[0]); fma4(a1, sc, vv[1]);
            const float4* ve = (const float4*)&VE[ks][jj][0];
            fma4(a2, sc, ve[0]); fma4(a3, sc, ve[1]);
        }
        float* rp = Rb + b * 38400 + 4800 * g + 1200 * u + 400 * k + 16 * i;
        ((float4*)rp)[0] = a0;
        ((float4*)rp)[1] = a1;
        a2.x *= 0.1f; a2.y *= 0.1f; a2.z *= 0.1f; a2.w *= 0.1f;
        a3.x *= 0.1f; a3.y *= 0.1f; a3.z *= 0.1f; a3.w *= 0.1f;
        ((float4*)rp)[2] = a2;
        ((float4*)rp)[3] = a3;
    }
}

// ---------------- K4: channel l2norm + pair-sum + unsort + hash softmax ----------------
__global__ __launch_bounds__(256) void k4_post(
        const float* __restrict__ Rb, const float* __restrict__ bsb,
        const int* __restrict__ idx_buf, float* __restrict__ fin) {
    __shared__ float D[300];
    __shared__ float bsn[300];
    __shared__ float retU[224][64];
    __shared__ float bsU[224];
    __shared__ int idxL[224];
    const int b = blockIdx.x, tid = threadIdx.x;
    const float* R = Rb + b * 38400;
    if (tid < 224) idxL[tid] = idx_buf[b * 224 + tid];
    for (int r = tid; r < 300; r += 256) {
        float s = 0.f;
        for (int c = 0; c < 128; ++c) { float v = R[c * 300 + r]; s += v * v; }
        D[r] = fmaxf(sqrtf(s), EPSN);
    }
    for (int idx = tid; idx < 300; idx += 256) {
        int u = idx / 75, t = idx % 75;
        float s2 = 0.f, sum = 0.f;
        #pragma unroll
        for (int g = 0; g < 8; ++g) {
            float v = bsb[b * 2400 + g * 300 + u * 75 + t];
            s2 += v * v; sum += v;
        }
        bsn[idx] = sum / fmaxf(sqrtf(s2), EPSN);
    }
    __syncthreads();
    for (int idx = tid; idx < 224 * 64; idx += 256) {
        int p = idx >> 6, o = idx & 63;
        int u3 = p / 56, t = p % 56;
        int k3 = t / 25, i3 = t % 25;
        int q0 = 9600 * u3 + 3200 * k3 + 128 * i3 + 2 * o;
        float2 rv = *(const float2*)&R[q0];
        float val = rv.x / D[q0 % 300] + rv.y / D[(q0 + 1) % 300];
        int r = idxL[p];
        retU[r][o] = val;
        if (o == 0) bsU[r] = bsn[u3 * 75 + t];
    }
    __syncthreads();
    for (int idx = tid; idx < 56 * 64; idx += 256) {
        int h = idx >> 6, o = idx & 63;
        float b0 = bsU[h], b1 = bsU[56 + h], b2 = bsU[112 + h], b3 = bsU[168 + h];
        float m = fmaxf(fmaxf(b0, b1), fmaxf(b2, b3));
        float e0 = expf(b0 - m), e1 = expf(b1 - m), e2 = expf(b2 - m), e3 = expf(b3 - m);
        float ps = e0 + e1 + e2 + e3;
        float val = (retU[h][o] * e0 + retU[56 + h][o] * e1 +
                     retU[112 + h][o] * e2 + retU[168 + h][o] * e3) / ps;
        fin[b * 3584 + h * 64 + o] = val;
    }
}

// ---------------- K5: (b,h,o) -> (n,o,h,w) transpose, FP32 output ----------------
__global__ __launch_bounds__(256) void k5_out(
        const float* __restrict__ fin, float* __restrict__ out) {
    int idx = blockIdx.x * 256 + threadIdx.x;
    if (idx >= 401408) return;
    int w = idx % 56, h = (idx / 56) % 56, o = (idx / 3136) % 64, n = idx / 200704;
    out[idx] = fin[(n * 56 + w) * 3584 + h * 64 + o];
}

extern "C" void kernel_launch(void* const* d_in, const int* in_sizes, int n_in,
                              void* d_out, int out_size, void* d_ws, size_t ws_size,
                              hipStream_t stream) {
    (void)in_sizes; (void)n_in; (void)out_size; (void)ws_size;
    const float* x     = (const float*)d_in[0];
    const float* cw    = (const float*)d_in[1];
    const float* gamma = (const float*)d_in[2];
    const float* beta  = (const float*)d_in[3];
    const float* rel   = (const float*)d_in[4];
    const float* rot   = (const float*)d_in[5];
    float* ws  = (float*)d_ws;
    float* qkv = ws;
    float* bsb = ws + 602112;
    float* Rb  = ws + 870912;
    float* fin = ws + 5171712;
    int*   idx = (int*)(ws + 5573120);

    k1_qkv<<<112, 256, 0, stream>>>(x, cw, gamma, beta, qkv);
    k2_sort<<<112, 256, 0, stream>>>(qkv, rot, idx);
    k3_attn<<<dim3(112, 4, 3), 256, 0, stream>>>(qkv, idx, rel, Rb, bsb);
    k4_post<<<112, 256, 0, stream>>>(Rb, bsb, idx, fin);
    k5_out<<<1568, 256, 0, stream>>>(fin, (float*)d_out);
}

// Round 12
// 181.271 us; speedup vs baseline: 1.1870x; 1.1870x over previous
//
#include <hip/hip_runtime.h>
#include <math.h>

// ============================================================================
// Sizes (fixed): N=2, C=64, Hax=56, W=56 -> B=112, H=56, OUT=64, N_HASHES=4,
// CHUNK=25, GROUPS=8, GP=8, hash_buckets=2, padding=19, K=3, qkv ch=96.
// Inputs fp32; OUTPUT FP32; stable argsort tie order (established R8-R11).
// R11 baseline: 215 us total, k3=89 us (VALUBusy 59%, Occ 17%, LDS 42.5KB).
// R12: k3 algebra (Wc fold, hw exp, post-scale), float4 gathers, k1+k2 and
// k4+k5 fusions (5 launches -> 3).
//
// ws layout (float slots):
//   qkv : [112][5376]   off 0
//   bsb : [112][2400]   off 602112
//   Rb  : [112][38400]  off 870912
//   idx : [112][224]    off 5171712  (int)
// ============================================================================

#define EPSN 5e-5f
#define LOG2E 1.4426950408889634f
#define LN2   0.6931471805599453f

__device__ __forceinline__ float dot4(const float4 a, const float4 b) {
    return a.x * b.x + a.y * b.y + a.z * b.z + a.w * b.w;
}
__device__ __forceinline__ void fma4(float4& a, float s, const float4 v) {
    a.x += s * v.x; a.y += s * v.y; a.z += s * v.z; a.w += s * v.w;
}

// ---------------- K12: qkv GEMM + BN + LSH codes + stable argsort ----------------
__global__ __launch_bounds__(256) void k12_qkv_sort(
        const float* __restrict__ x, const float* __restrict__ cw,
        const float* __restrict__ gamma, const float* __restrict__ beta,
        const float* __restrict__ rot, float* __restrict__ qkv,
        int* __restrict__ idx_buf) {
    __shared__ float xs[64 * 56];    // [c][h]
    __shared__ float cws[96 * 64];
    __shared__ float wm[56 * 32];    // w_match[t][f]
    __shared__ float rl[128];
    __shared__ float gs[96], bt[96];
    __shared__ int code[224];
    __shared__ int srt[224];
    const int b = blockIdx.x, n = b / 56, w = b % 56, tid = threadIdx.x;
    const float* xb = x + n * 200704 + w;
    for (int i = tid; i < 3584; i += 256) {
        int c = i / 56, h = i % 56;
        xs[i] = xb[c * 3136 + h * 56];
    }
    for (int i = tid; i < 6144; i += 256) cws[i] = cw[i];
    if (tid < 128) rl[tid] = rot[tid];
    if (tid < 96) { gs[tid] = gamma[tid]; bt[tid] = beta[tid]; }
    __syncthreads();
    const float inv_s = 1.0f / sqrtf(1.0f + 1.0e-5f);
    for (int j = tid; j < 5376; j += 256) {      // j = o*56 + h (flat)
        int o = j / 56, h = j % 56;
        float s = 0.f;
        #pragma unroll 8
        for (int c = 0; c < 64; ++c) s += cws[o * 64 + c] * xs[c * 56 + h];
        float val = s * inv_s * gs[o] + bt[o];
        qkv[b * 5376 + j] = val;
        int f = j % 96;                          // (B,96,56)->(B,56,96) raw reshape
        if (f < 32) wm[(j / 96) * 32 + f] = val;
    }
    __syncthreads();
    if (tid < 224) {
        int u = tid / 56, t = tid % 56;
        float s = 0.f;
        #pragma unroll 8
        for (int f = 0; f < 32; ++f) s += wm[t * 32 + f] * rl[f * 4 + u];
        code[tid] = ((s < 0.f) ? 1 : 0) + 2 * u; // argmax([s,-s]) + u*hash_buckets
    }
    __syncthreads();
    if (tid < 224) {
        int c = code[tid], r = 0;
        for (int p = 0; p < 224; ++p) {
            int cp = code[p];
            r += (int)((cp < c) | ((cp == c) & (p < tid)));  // stable rank
        }
        srt[r] = tid;
    }
    __syncthreads();
    if (tid < 224) idx_buf[b * 224 + tid] = srt[tid];
}

// ---------------- K3: chunked attention, one block per (b,u,k) ----------------
// LDS 49.5KB -> 3 blocks/CU. Final-phase algebra:
//   ss = dot(wb_i, WbN_j + 0.1*WE_j) * DI_ij   (Wc fold, single dot4)
__global__ __launch_bounds__(256) void k3_attn(
        const float* __restrict__ qkv, const int* __restrict__ idx_buf,
        const float* __restrict__ rel, float* __restrict__ Rb,
        float* __restrict__ bsb) {
    __shared__ __align__(16) float Wb [8][3][25][4];  // raw w_b
    __shared__ __align__(16) float WbN[8][3][25][4];  // normalized, then Wc in place
    __shared__ __align__(16) float Vb [8][3][25][8];
    __shared__ __align__(16) float WE [3][25][4];     // 0.1 * w_emb
    __shared__ __align__(16) float VE [3][25][8];
    __shared__ float DI[25][75];
    const int b = blockIdx.x, u = blockIdx.y, k = blockIdx.z;
    const int tid = threadIdx.x;
    const int km1 = (k + 2) % 3, kp1 = (k + 1) % 3;
    const float* q = qkv + b * 5376;
    const int* ib = idx_buf + b * 224;

    // Wb gather: each (g,kk,i) fragment is 4 contiguous floats in qkv
    // (f0 = (16g+12u+4kk+4i)%32, multiple of 4, <=28: never crosses a t-row)
    for (int idx = tid; idx < 600; idx += 256) {
        int i = idx % 25, kk = (idx / 25) % 3, g = idx / 75;
        int p0 = 1200 * g + 300 * u + 100 * kk + 4 * i;
        int h = p0 / 2400, r = p0 % 2400, t = r >> 5, f = r & 31;
        int row = (t < 56) ? t : t - 19;
        int tt = ib[h * 56 + row] % 56;
        *(float4*)&Wb[g][kk][i][0] = *(const float4*)&q[tt * 96 + f];
    }
    // Vb gather: 8 contiguous floats per fragment, loaded as 2 float4 halves
    for (int idx = tid; idx < 1200; idx += 256) {
        int half = idx & 1, fr = idx >> 1;
        int i = fr % 25, kk = (fr / 25) % 3, g = fr / 75;
        int p0 = 2400 * g + 600 * u + 200 * kk + 8 * i + 4 * half;
        int h = p0 / 4800, r = p0 % 4800, t = r >> 6, f = r & 63;
        int row = (t < 56) ? t : t - 19;
        int tt = ib[h * 56 + row] % 56;
        *(float4*)&Vb[g][kk][i][4 * half] = *(const float4*)&q[tt * 96 + 32 + f];
    }
    for (int idx = tid; idx < 75; idx += 256) {
        int i = idx % 25, kk = idx / 25;
        int t = kk * 25 + i; int row = (t < 56) ? t : t - 19;
        float4 we = *(const float4*)&rel[row * 12];
        we.x *= 0.1f; we.y *= 0.1f; we.z *= 0.1f; we.w *= 0.1f;   // F_GW pre-scaled
        *(float4*)&WE[kk][i][0] = we;
    }
    for (int idx = tid; idx < 150; idx += 256) {
        int half = idx & 1, fr = idx >> 1;
        int i = fr % 25, kk = fr / 25;
        int t = kk * 25 + i; int row = (t < 56) ? t : t - 19;
        *(float4*)&VE[kk][i][4 * half] = *(const float4*)&rel[row * 12 + 4 + 4 * half];
    }
    __syncthreads();
    // WbN = Wb / max(||Wb||, eps)
    for (int idx = tid; idx < 600; idx += 256) {
        int i = idx % 25, kk = (idx / 25) % 3, g = idx / 75;
        float4 v = *(const float4*)&Wb[g][kk][i][0];
        float ni = 1.0f / fmaxf(sqrtf(dot4(v, v)), EPSN);
        v.x *= ni; v.y *= ni; v.z *= ni; v.w *= ni;
        *(float4*)&WbN[g][kk][i][0] = v;
    }
    __syncthreads();
    // DI: joint 16-vector l2 norm over (raw_g, emb_g) per (i,j)
    for (int idx = tid; idx < 1875; idx += 256) {
        int i = idx / 75, j = idx % 75;
        int jb = j / 25, jj = j % 25;
        int ks = (jb == 0) ? k : ((jb == 1) ? km1 : kp1);
        float4 we = *(const float4*)&WE[ks][jj][0];
        float s2 = 0.f;
        #pragma unroll
        for (int g = 0; g < 8; ++g) {
            float4 wb = *(const float4*)&Wb[g][k][i][0];
            float raw = dot4(wb, *(const float4*)&WbN[g][ks][jj][0]);
            float emb = dot4(wb, we);
            s2 += raw * raw + emb * emb;
        }
        DI[i][j] = 1.0f / fmaxf(sqrtf(s2), EPSN);
    }
    // register copy of raw wb for the final phase (Wb itself is never overwritten)
    const int g = tid & 7, i = tid >> 3;
    float4 wbr;
    if (tid < 200) wbr = *(const float4*)&Wb[g][k][i][0];
    __syncthreads();
    // Wc = WbN + WE (in place; single-dot4 score form)
    for (int idx = tid; idx < 600; idx += 256) {
        int i2 = idx % 25, kk = (idx / 25) % 3, g2 = idx / 75;
        float4 v = *(const float4*)&WbN[g2][kk][i2][0];
        float4 we = *(const float4*)&WE[kk][i2][0];
        v.x += we.x; v.y += we.y; v.z += we.z; v.w += we.w;
        *(float4*)&WbN[g2][kk][i2][0] = v;
    }
    __syncthreads();
    // softmax + PV, one thread per (g,i)
    if (tid < 200) {
        float ssv[75];
        float m = -INFINITY;
        #pragma unroll
        for (int j = 0; j < 75; ++j) {
            int jb = j / 25, jj = j % 25;
            int ks = (jb == 0) ? k : ((jb == 1) ? km1 : kp1);
            float v = dot4(wbr, *(const float4*)&WbN[g][ks][jj][0]) * DI[i][j];
            ssv[j] = v;
            m = fmaxf(m, v);
        }
        float se = 0.f;
        float4 a0 = {0,0,0,0}, a1 = {0,0,0,0}, a2 = {0,0,0,0}, a3 = {0,0,0,0};
        #pragma unroll
        for (int j = 0; j < 75; ++j) {
            int jb = j / 25, jj = j % 25;
            int ks = (jb == 0) ? k : ((jb == 1) ? km1 : kp1);
            float e = __builtin_amdgcn_exp2f((ssv[j] - m) * LOG2E);
            se += e;
            const float4* vv = (const float4*)&Vb[g][ks][jj][0];
            fma4(a0, e, vv[0]); fma4(a1, e, vv[1]);
            const float4* ve = (const float4*)&VE[ks][jj][0];
            fma4(a2, e, ve[0]); fma4(a3, e, ve[1]);
        }
        bsb[b * 2400 + g * 300 + u * 75 + k * 25 + i] =
            m + __builtin_amdgcn_logf(se) * LN2;
        const float rinv = 1.0f / se;
        const float r2 = 0.1f * rinv;            // F_GV1
        a0.x *= rinv; a0.y *= rinv; a0.z *= rinv; a0.w *= rinv;
        a1.x *= rinv; a1.y *= rinv; a1.z *= rinv; a1.w *= rinv;
        a2.x *= r2;   a2.y *= r2;   a2.z *= r2;   a2.w *= r2;
        a3.x *= r2;   a3.y *= r2;   a3.z *= r2;   a3.w *= r2;
        float* rp = Rb + b * 38400 + 4800 * g + 1200 * u + 400 * k + 16 * i;
        ((float4*)rp)[0] = a0;
        ((float4*)rp)[1] = a1;
        ((float4*)rp)[2] = a2;
        ((float4*)rp)[3] = a3;
    }
}

// ---------------- K45: channel l2norm + pair-sum + unsort + hash softmax
//                        + transposed FP32 store ----------------
__global__ __launch_bounds__(256) void k45_post(
        const float* __restrict__ Rb, const float* __restrict__ bsb,
        const int* __restrict__ idx_buf, float* __restrict__ out) {
    __shared__ float D[300];
    __shared__ float bsn[300];
    __shared__ float retU[224][64];
    __shared__ float bsU[224];
    __shared__ int idxL[224];
    const int b = blockIdx.x, tid = threadIdx.x;
    const int n = b / 56, w = b % 56;
    const float* R = Rb + b * 38400;
    if (tid < 224) idxL[tid] = idx_buf[b * 224 + tid];
    for (int r = tid; r < 300; r += 256) {
        float s = 0.f;
        for (int c = 0; c < 128; ++c) { float v = R[c * 300 + r]; s += v * v; }
        D[r] = fmaxf(sqrtf(s), EPSN);
    }
    for (int idx = tid; idx < 300; idx += 256) {
        int u = idx / 75, t = idx % 75;
        float s2 = 0.f, sum = 0.f;
        #pragma unroll
        for (int g = 0; g < 8; ++g) {
            float v = bsb[b * 2400 + g * 300 + u * 75 + t];
            s2 += v * v; sum += v;
        }
        bsn[idx] = sum / fmaxf(sqrtf(s2), EPSN);
    }
    __syncthreads();
    for (int idx = tid; idx < 224 * 64; idx += 256) {
        int p = idx >> 6, o = idx & 63;
        int u3 = p / 56, t = p % 56;
        int k3 = t / 25, i3 = t % 25;
        int q0 = 9600 * u3 + 3200 * k3 + 128 * i3 + 2 * o;
        float2 rv = *(const float2*)&R[q0];
        float val = rv.x / D[q0 % 300] + rv.y / D[(q0 + 1) % 300];
        int r = idxL[p];
        retU[r][o] = val;
        if (o == 0) bsU[r] = bsn[u3 * 75 + t];
    }
    __syncthreads();
    for (int idx = tid; idx < 56 * 64; idx += 256) {
        int h = idx >> 6, o = idx & 63;
        float b0 = bsU[h], b1 = bsU[56 + h], b2 = bsU[112 + h], b3 = bsU[168 + h];
        float m = fmaxf(fmaxf(b0, b1), fmaxf(b2, b3));
        float e0 = __builtin_amdgcn_exp2f((b0 - m) * LOG2E);
        float e1 = __builtin_amdgcn_exp2f((b1 - m) * LOG2E);
        float e2 = __builtin_amdgcn_exp2f((b2 - m) * LOG2E);
        float e3 = __builtin_amdgcn_exp2f((b3 - m) * LOG2E);
        float ps = e0 + e1 + e2 + e3;
        float val = (retU[h][o] * e0 + retU[56 + h][o] * e1 +
                     retU[112 + h][o] * e2 + retU[168 + h][o] * e3) / ps;
        out[((n * 64 + o) * 56 + h) * 56 + w] = val;   // (n,o,h,w) transposed store
    }
}

extern "C" void kernel_launch(void* const* d_in, const int* in_sizes, int n_in,
                              void* d_out, int out_size, void* d_ws, size_t ws_size,
                              hipStream_t stream) {
    (void)in_sizes; (void)n_in; (void)out_size; (void)ws_size;
    const float* x     = (const float*)d_in[0];
    const float* cw    = (const float*)d_in[1];
    const float* gamma = (const float*)d_in[2];
    const float* beta  = (const float*)d_in[3];
    const float* rel   = (const float*)d_in[4];
    const float* rot   = (const float*)d_in[5];
    float* ws  = (float*)d_ws;
    float* qkv = ws;
    float* bsb = ws + 602112;
    float* Rb  = ws + 870912;
    int*   idx = (int*)(ws + 5171712);

    k12_qkv_sort<<<112, 256, 0, stream>>>(x, cw, gamma, beta, rot, qkv, idx);
    k3_attn<<<dim3(112, 4, 3), 256, 0, stream>>>(qkv, idx, rel, Rb, bsb);
    k45_post<<<112, 256, 0, stream>>>(Rb, bsb, idx, (float*)d_out);
}